// Round 10
// baseline (69.293 us; speedup 1.0000x reference)
//
#include <hip/hip_runtime.h>
#include <stdint.h>

// pooled[b,o] = x[b,:] . Wp[o,:] + biasp[o] + 0.25*(y[b,n0]+y[b,n0+1]+y[b,n0+64]+y[b,n0+65])
//   o = p*32+q, n0 = 128p+2q; Wp = 2x2-pooled W rows. out = pooled / mean(pooled).
// 3 dispatches: prep (pool W/bias only) -> gemm (128x128, 8 waves, dbuf LDS;
// A staged from f32 x with in-loop cvt_pk->swizzled ds_write (prep x-pass
// deleted); B via source-swizzled global_load_lds; y interleaved lag-1;
// counted vmcnt ledger [A4,B2,Y4]) -> norm (redundant reduce + scale).

#define KDIM 1024
#define NP   1024
#define BM 128
#define BN 128
#define BK 64

typedef __bf16 bf16x8 __attribute__((ext_vector_type(8)));
typedef float f32x4 __attribute__((ext_vector_type(4)));
typedef _Float16 f16x4 __attribute__((ext_vector_type(4)));

__device__ __forceinline__ unsigned f2bf(float f) {
  union { float f; unsigned u; } v; v.f = f;
  unsigned r = v.u + 0x7fffu + ((v.u >> 16) & 1u);  // RNE
  return r >> 16;
}

__device__ __forceinline__ void gload_lds16(const void* g, void* l) {
  __builtin_amdgcn_global_load_lds(
      (const __attribute__((address_space(1))) void*)g,
      (__attribute__((address_space(3))) void*)l, 16, 0, 0);
}

// ---- kernel 1: pool W rows -> wp bf16, pool bias ----
__global__ void k_prep(const float* __restrict__ W, const float* __restrict__ bias,
                       unsigned short* __restrict__ wp, float* __restrict__ biasp) {
  int o = blockIdx.x;  // pooled feature index
  int t = threadIdx.x;
  int r0 = ((o >> 5) << 7) + ((o & 31) << 1);
  const float4* W4 = (const float4*)W;
  float4 w0 = W4[(r0) * 256 + t];
  float4 w1 = W4[(r0 + 1) * 256 + t];
  float4 w2 = W4[(r0 + 64) * 256 + t];
  float4 w3 = W4[(r0 + 65) * 256 + t];
  float ax = 0.25f * (w0.x + w1.x + w2.x + w3.x);
  float ay = 0.25f * (w0.y + w1.y + w2.y + w3.y);
  float az = 0.25f * (w0.z + w1.z + w2.z + w3.z);
  float aw = 0.25f * (w0.w + w1.w + w2.w + w3.w);
  uint2 pk;
  pk.x = f2bf(ax) | (f2bf(ay) << 16);
  pk.y = f2bf(az) | (f2bf(aw) << 16);
  ((uint2*)wp)[o * 256 + t] = pk;
  if (t == 0)
    biasp[o] = 0.25f * (bias[r0] + bias[r0 + 1] + bias[r0 + 64] + bias[r0 + 65]);
}

// ---- kernel 2: GEMM; A from f32 x (in-loop cvt), B gload_lds, y interleaved ----
__global__ __launch_bounds__(512, 4) void k_gemm(
    const float* __restrict__ x, const unsigned short* __restrict__ wp,
    const float* __restrict__ biasp, const float* __restrict__ y,
    float* __restrict__ out, _Float16* __restrict__ ph,
    float* __restrict__ partials, int use16) {
  // buf in {0,1}: As(buf)=smem+buf*32768 (16KB), Bs(buf)=+16384
  __shared__ char smem[65536];

  int bid = blockIdx.x;
  int wg = (bid & 7) * 64 + (bid >> 3);  // XCD swizzle, 512 = 8*64 bijective
  int bm0 = (wg >> 3) * BM;
  int bn0 = (wg & 7) * BN;

  int tid = threadIdx.x;
  int lane = tid & 63;
  int wid = tid >> 6;               // 0..7
  int wr = wid >> 1, wc = wid & 1;  // wave tile 32x64

  f32x4 acc[2][4];
#pragma unroll
  for (int i = 0; i < 2; i++)
#pragma unroll
    for (int j = 0; j < 4; j++) acc[i][j] = (f32x4)0.0f;

  // A reg-staging: thread t handles row arow=t>>2 (0..127), k-seg aseg=t&3
  // (16 f32 = 64B per step). Dest: 2 swizzled 16B chunks (write-side XOR).
  int arow = tid >> 2;
  int aseg = tid & 3;
  const float* aBase = x + (size_t)(bm0 + arow) * KDIM + aseg * 16;
  int awAddr0 = arow * 128 + (((aseg * 2) ^ (arow & 7)) << 4);
  int awAddr1 = arow * 128 + (((aseg * 2 + 1) ^ (arow & 7)) << 4);

  // B staging (as r9): source col chunk pre-swizzled by (lane&7)^(lane>>3).
  int srow = tid >> 3;
  int scol = (((lane & 7) ^ (lane >> 3)) << 3);
  const unsigned short* bSrc = wp + (size_t)(bn0 + srow) * KDIM + scol;
  int ldsOff = wid * 1024;

  int rbase = (lane & 15) * 128;
  int xorv = (lane & 7) << 4;
  int cb0 = (((lane >> 4) * 16)) ^ xorv;
  int cb1 = ((64 + (lane >> 4) * 16)) ^ xorv;

  // y interleave (lag-1, 2-slot window). output q = mi*16+ni*4+j.
  const float2* y2 = (const float2*)y;
  int r_l = (lane >> 4) * 4;
  int c_l = lane & 15;
  int yrow0 = bm0 + wr * 32 + r_l;
  int yb[4];
#pragma unroll
  for (int ni = 0; ni < 4; ++ni) {
    int col = bn0 + wc * 64 + ni * 16 + c_l;
    yb[ni] = ((col >> 5) << 6) + (col & 31);
  }
  float2 yin[2][4];
  float4 a_in[4];

#define ALOAD(ks)                                                              \
  {                                                                            \
    const float* ap = aBase + (ks) * BK;                                       \
    asm volatile("global_load_dwordx4 %0, %1, off"                             \
                 : "=v"(a_in[0]) : "v"(ap) : "memory");                        \
    asm volatile("global_load_dwordx4 %0, %1, off offset:16"                   \
                 : "=v"(a_in[1]) : "v"(ap) : "memory");                        \
    asm volatile("global_load_dwordx4 %0, %1, off offset:32"                   \
                 : "=v"(a_in[2]) : "v"(ap) : "memory");                        \
    asm volatile("global_load_dwordx4 %0, %1, off offset:48"                   \
                 : "=v"(a_in[3]) : "v"(ap) : "memory");                        \
  }

#define ACVT_WRITE(buf)                                                        \
  {                                                                            \
    uint4 w0, w1;                                                              \
    asm("v_cvt_pk_bf16_f32 %0, %1, %2" : "=v"(w0.x) : "v"(a_in[0].x), "v"(a_in[0].y)); \
    asm("v_cvt_pk_bf16_f32 %0, %1, %2" : "=v"(w0.y) : "v"(a_in[0].z), "v"(a_in[0].w)); \
    asm("v_cvt_pk_bf16_f32 %0, %1, %2" : "=v"(w0.z) : "v"(a_in[1].x), "v"(a_in[1].y)); \
    asm("v_cvt_pk_bf16_f32 %0, %1, %2" : "=v"(w0.w) : "v"(a_in[1].z), "v"(a_in[1].w)); \
    asm("v_cvt_pk_bf16_f32 %0, %1, %2" : "=v"(w1.x) : "v"(a_in[2].x), "v"(a_in[2].y)); \
    asm("v_cvt_pk_bf16_f32 %0, %1, %2" : "=v"(w1.y) : "v"(a_in[2].z), "v"(a_in[2].w)); \
    asm("v_cvt_pk_bf16_f32 %0, %1, %2" : "=v"(w1.z) : "v"(a_in[3].x), "v"(a_in[3].y)); \
    asm("v_cvt_pk_bf16_f32 %0, %1, %2" : "=v"(w1.w) : "v"(a_in[3].z), "v"(a_in[3].w)); \
    *(uint4*)(smem + (buf) * 32768 + awAddr0) = w0;                            \
    *(uint4*)(smem + (buf) * 32768 + awAddr1) = w1;                            \
  }

#define BSTAGE(buf, ks)                                                        \
  {                                                                            \
    int k0 = (ks) * BK;                                                        \
    char* bb = smem + (buf) * 32768 + 16384 + ldsOff;                          \
    gload_lds16(bSrc + (size_t)0 * 64 * KDIM + k0, bb + 0 * 8192);             \
    gload_lds16(bSrc + (size_t)1 * 64 * KDIM + k0, bb + 1 * 8192);             \
  }

#define YLD(p, s, q)                                                           \
  {                                                                            \
    const float2* pp = y2 +                                                    \
        (size_t)(yrow0 + (((q) >> 4) * 16) + ((q) & 3)) * 2048 +               \
        yb[((q) >> 2) & 3];                                                    \
    asm volatile("global_load_dwordx2 %0, %1, off"                             \
                 : "=v"(yin[(p) % 2][s]) : "v"(pp) : "memory");                \
    asm volatile("global_load_dwordx2 %0, %1, off offset:256"                  \
                 : "=v"(yin[(p) % 2][(s) + 1]) : "v"(pp) : "memory");          \
  }
#define YLOAD(p) { YLD(p, 0, 2 * (p)) YLD(p, 2, 2 * (p) + 1) }
#define YCONS(p)                                                               \
  {                                                                            \
    acc[(2 * (p)) >> 4][((2 * (p)) >> 2) & 3][(2 * (p)) & 3] +=                \
        0.25f * ((yin[(p) % 2][0].x + yin[(p) % 2][0].y) +                     \
                 (yin[(p) % 2][1].x + yin[(p) % 2][1].y));                     \
    acc[(2 * (p) + 1) >> 4][((2 * (p) + 1) >> 2) & 3][(2 * (p) + 1) & 3] +=    \
        0.25f * ((yin[(p) % 2][2].x + yin[(p) % 2][2].y) +                     \
                 (yin[(p) % 2][3].x + yin[(p) % 2][3].y));                     \
  }

#define COMPUTE(cur)                                                           \
  {                                                                            \
    const char* Ab = smem + (cur) * 32768;                                     \
    const char* Bb = Ab + 16384;                                               \
    _Pragma("unroll")                                                          \
    for (int kk = 0; kk < 2; ++kk) {                                           \
      int cb = kk ? cb1 : cb0;                                                 \
      bf16x8 af[2], bfr[4];                                                    \
      _Pragma("unroll")                                                        \
      for (int mi = 0; mi < 2; ++mi)                                           \
        af[mi] = *(const bf16x8*)(Ab + (wr * 32 + mi * 16) * 128 + rbase + cb);\
      _Pragma("unroll")                                                        \
      for (int ni = 0; ni < 4; ++ni)                                           \
        bfr[ni] = *(const bf16x8*)(Bb + (wc * 64 + ni * 16) * 128 + rbase + cb);\
      _Pragma("unroll")                                                        \
      for (int mi = 0; mi < 2; ++mi)                                           \
        _Pragma("unroll")                                                      \
        for (int ni = 0; ni < 4; ++ni)                                         \
          acc[mi][ni] = __builtin_amdgcn_mfma_f32_16x16x32_bf16(               \
              af[mi], bfr[ni], acc[mi][ni], 0, 0, 0);                          \
    }                                                                          \
  }

  // vmcnt ledger: per iter issue [A4, B2, Y4] = 10 events.
  //  open  vmcnt(10): newest 10 = A_{i+1},B_{i+1},Y_i -> B_i, Y_{i-1} retired.
  //  post  vmcnt(6):  newest 6  = B_{i+1},Y_i         -> A_{i+1} retired.
  //  lgkmcnt(0) before closing barrier drains A ds_writes.
#define KITER(ks, OPENWAIT)                                                    \
  {                                                                            \
    if ((ks) < 15) { ALOAD((ks) + 1); BSTAGE(((ks) + 1) & 1, (ks) + 1); }      \
    YLOAD(ks);                                                                 \
    asm volatile(OPENWAIT ::: "memory");                                       \
    __builtin_amdgcn_s_barrier();                                              \
    COMPUTE((ks) & 1);                                                         \
    __builtin_amdgcn_sched_barrier(0);                                         \
    if ((ks) < 15) {                                                           \
      asm volatile("s_waitcnt vmcnt(6)" ::: "memory");                         \
      __builtin_amdgcn_sched_barrier(0);                                       \
      ACVT_WRITE(((ks) + 1) & 1);                                              \
    }                                                                          \
    if ((ks) >= 1) YCONS((ks) - 1);                                            \
    asm volatile("s_waitcnt lgkmcnt(0)" ::: "memory");                         \
    __builtin_amdgcn_s_barrier();                                              \
  }

  // prologue: A_0 load+cvt+write, B_0 stage
  ALOAD(0);
  asm volatile("s_waitcnt vmcnt(0)" ::: "memory");
  __builtin_amdgcn_sched_barrier(0);
  ACVT_WRITE(0);
  BSTAGE(0, 0);

  KITER(0,  "s_waitcnt vmcnt(10) lgkmcnt(0)")
  KITER(1,  "s_waitcnt vmcnt(10)")
  KITER(2,  "s_waitcnt vmcnt(10)")
  KITER(3,  "s_waitcnt vmcnt(10)")
  KITER(4,  "s_waitcnt vmcnt(10)")
  KITER(5,  "s_waitcnt vmcnt(10)")
  KITER(6,  "s_waitcnt vmcnt(10)")
  KITER(7,  "s_waitcnt vmcnt(10)")
  KITER(8,  "s_waitcnt vmcnt(10)")
  KITER(9,  "s_waitcnt vmcnt(10)")
  KITER(10, "s_waitcnt vmcnt(10)")
  KITER(11, "s_waitcnt vmcnt(10)")
  KITER(12, "s_waitcnt vmcnt(10)")
  KITER(13, "s_waitcnt vmcnt(10)")
  KITER(14, "s_waitcnt vmcnt(10)")
  KITER(15, "s_waitcnt vmcnt(4)")

  asm volatile("s_waitcnt vmcnt(0)" ::: "memory");
  __builtin_amdgcn_sched_barrier(0);
  YCONS(15);

  // epilogue: acc holds gemm + pooled y; add bias, store, block sum
  float tsum = 0.f;
  float bpv[4];
#pragma unroll
  for (int ni = 0; ni < 4; ++ni) bpv[ni] = biasp[bn0 + wc * 64 + ni * 16 + c_l];
#pragma unroll
  for (int mi = 0; mi < 2; ++mi) {
#pragma unroll
    for (int ni = 0; ni < 4; ++ni) {
      int col = bn0 + wc * 64 + ni * 16 + c_l;
#pragma unroll
      for (int j = 0; j < 4; ++j) {
        int row = bm0 + wr * 32 + mi * 16 + r_l + j;
        float val = acc[mi][ni][j] + bpv[ni];
        size_t o = (size_t)row * NP + col;
        if (use16) ph[o] = (_Float16)val;
        else out[o] = val;
        tsum += val;
      }
    }
  }
#pragma unroll
  for (int off = 32; off > 0; off >>= 1) tsum += __shfl_down(tsum, off);
  float* sm = (float*)smem;
  __syncthreads();
  if (lane == 0) sm[wid] = tsum;
  __syncthreads();
  if (tid == 0)
    partials[bid] = ((sm[0] + sm[1]) + (sm[2] + sm[3])) +
                    ((sm[4] + sm[5]) + (sm[6] + sm[7]));
}

// ---- kernel 3: redundant per-block reduce of 512 partials; scale to f32 out ----
__global__ void k_norm(float* __restrict__ out, const _Float16* __restrict__ ph,
                       const float* __restrict__ partials, int use16) {
  __shared__ float s[256];
  int t = threadIdx.x;
  s[t] = partials[t] + partials[t + 256];
  __syncthreads();
#pragma unroll
  for (int off = 128; off > 0; off >>= 1) {
    if (t < off) s[t] += s[t + off];
    __syncthreads();
  }
  float inv = 8388608.0f / s[0];  // (B*NP)/total
  int i = blockIdx.x * 256 + t;   // float4 index
  float4* o4 = (float4*)out;
  if (use16) {
    f16x4 hv = ((const f16x4*)ph)[i];
    float4 v;
    v.x = (float)hv[0] * inv;
    v.y = (float)hv[1] * inv;
    v.z = (float)hv[2] * inv;
    v.w = (float)hv[3] * inv;
    o4[i] = v;
  } else {
    float4 v = o4[i];
    v.x *= inv; v.y *= inv; v.z *= inv; v.w *= inv;
    o4[i] = v;
  }
}

extern "C" void kernel_launch(void* const* d_in, const int* in_sizes, int n_in,
                              void* d_out, int out_size, void* d_ws, size_t ws_size,
                              hipStream_t stream) {
  (void)in_sizes; (void)n_in; (void)out_size;
  const float* x = (const float*)d_in[0];
  const float* y = (const float*)d_in[1];
  const float* W = (const float*)d_in[2];
  const float* bias = (const float*)d_in[3];
  float* out = (float*)d_out;

  char* ws = (char*)d_ws;
  unsigned short* wp = (unsigned short*)(ws);       // 2 MiB
  float* biasp = (float*)(ws + 2097152);            // 4 KiB
  float* partials = (float*)(ws + 2097152 + 4096);  // 2 KiB
  _Float16* ph = (_Float16*)(ws + 4194304);         // 16 MiB
  int use16 = (ws_size >= (size_t)4194304 + 16777216) ? 1 : 0;

  hipLaunchKernelGGL(k_prep, dim3(1024), dim3(256), 0, stream, W, bias, wp, biasp);
  hipLaunchKernelGGL(k_gemm, dim3(512), dim3(512), 0, stream, x, wp, biasp, y, out, ph, partials, use16);
  hipLaunchKernelGGL(k_norm, dim3(8192), dim3(256), 0, stream, out, ph, partials, use16);
}

// Round 11
// 57.307 us; speedup vs baseline: 1.2091x; 1.2091x over previous
//
#include <hip/hip_runtime.h>
#include <stdint.h>

// pooled[b,o] = x[b,:] . Wp[o,:] + biasp[o] + 0.25*(y[b,n0]+y[b,n0+1]+y[b,n0+64]+y[b,n0+65])
//   o = p*32+q, n0 = 128p+2q; Wp = 2x2-pooled W rows. out = pooled / mean(pooled).
// 3 dispatches: prep (x->bf16 + pool W/bias) -> gemm (256x128 tile, 8 waves,
// dbuf LDS, ONE barrier + ONE counted vmcnt(8) per K-tile, 2 setprio'd MFMA
// clusters per tile, y interleaved lag-2 into acc) -> norm (reduce + scale).

#define KDIM 1024
#define NP   1024
#define BM 256
#define BN 128
#define BK 64
#define NBLK 256

typedef __bf16 bf16x8 __attribute__((ext_vector_type(8)));
typedef float f32x4 __attribute__((ext_vector_type(4)));
typedef _Float16 f16x4 __attribute__((ext_vector_type(4)));

__device__ __forceinline__ unsigned f2bf(float f) {
  union { float f; unsigned u; } v; v.f = f;
  unsigned r = v.u + 0x7fffu + ((v.u >> 16) & 1u);  // RNE
  return r >> 16;
}

__device__ __forceinline__ void gload_lds16(const void* g, void* l) {
  __builtin_amdgcn_global_load_lds(
      (const __attribute__((address_space(1))) void*)g,
      (__attribute__((address_space(3))) void*)l, 16, 0, 0);
}

// ---- kernel 1 (merged prep): x fp32->bf16 (blocks 0..4095), pool W+bias ----
__global__ void k_prep(const float* __restrict__ x, const float* __restrict__ W,
                       const float* __restrict__ bias,
                       unsigned short* __restrict__ xb, unsigned short* __restrict__ wp,
                       float* __restrict__ biasp) {
  int b = blockIdx.x;
  int t = threadIdx.x;
  if (b < 4096) {
    int i = b * 256 + t;  // 8 elems per thread
    const float4* x4 = (const float4*)x;
    float4 a = x4[i * 2], c = x4[i * 2 + 1];
    uint4 o;
    o.x = f2bf(a.x) | (f2bf(a.y) << 16);
    o.y = f2bf(a.z) | (f2bf(a.w) << 16);
    o.z = f2bf(c.x) | (f2bf(c.y) << 16);
    o.w = f2bf(c.z) | (f2bf(c.w) << 16);
    ((uint4*)xb)[i] = o;
  } else {
    int o = b - 4096;  // pooled feature index
    int r0 = ((o >> 5) << 7) + ((o & 31) << 1);
    const float4* W4 = (const float4*)W;
    float4 w0 = W4[(r0) * 256 + t];
    float4 w1 = W4[(r0 + 1) * 256 + t];
    float4 w2 = W4[(r0 + 64) * 256 + t];
    float4 w3 = W4[(r0 + 65) * 256 + t];
    float ax = 0.25f * (w0.x + w1.x + w2.x + w3.x);
    float ay = 0.25f * (w0.y + w1.y + w2.y + w3.y);
    float az = 0.25f * (w0.z + w1.z + w2.z + w3.z);
    float aw = 0.25f * (w0.w + w1.w + w2.w + w3.w);
    uint2 pk;
    pk.x = f2bf(ax) | (f2bf(ay) << 16);
    pk.y = f2bf(az) | (f2bf(aw) << 16);
    ((uint2*)wp)[o * 256 + t] = pk;
    if (t == 0)
      biasp[o] = 0.25f * (bias[r0] + bias[r0 + 1] + bias[r0 + 64] + bias[r0 + 65]);
  }
}

// ---- kernel 2: GEMM 256x128, 1 barrier + 1 vmcnt per K-tile ----
__global__ __launch_bounds__(512, 2) void k_gemm(
    const unsigned short* __restrict__ xb, const unsigned short* __restrict__ wp,
    const float* __restrict__ biasp, const float* __restrict__ y,
    float* __restrict__ out, _Float16* __restrict__ ph,
    float* __restrict__ partials, int use16) {
  // buf in {0,1}: A(buf)=smem+buf*49152 (32KB), B(buf)=+32768 (16KB)
  __shared__ char smem[98304];

  int bid = blockIdx.x;
  int wg = (bid & 7) * 32 + (bid >> 3);  // XCD swizzle, 256 = 8*32 bijective
  int bm0 = (wg >> 3) * BM;   // 32 row tiles
  int bn0 = (wg & 7) * BN;    // 8 col tiles

  int tid = threadIdx.x;
  int lane = tid & 63;
  int wid = tid >> 6;               // 0..7
  int wr = wid >> 1, wc = wid & 1;  // wave tile 64x64: rows wr*64, cols wc*64

  f32x4 acc[4][4];
#pragma unroll
  for (int i = 0; i < 4; i++)
#pragma unroll
    for (int j = 0; j < 4; j++) acc[i][j] = (f32x4)0.0f;

  // staging: 512 thr x 16B = 8KB/call; A 32KB = 4 calls, B 16KB = 2 calls.
  // LDS dest linear; SOURCE col chunk pre-swizzled by (lane&7)^(lane>>3).
  int srow = tid >> 3;  // 0..63
  int scol = (((lane & 7) ^ (lane >> 3)) << 3);
  const unsigned short* aSrc = xb + (size_t)(bm0 + srow) * KDIM + scol;
  const unsigned short* bSrc = wp + (size_t)(bn0 + srow) * KDIM + scol;
  int ldsOff = wid * 1024;

  int rbase = (lane & 15) * 128;
  int xorv = (lane & 7) << 4;
  int cb0 = (((lane >> 4) * 16)) ^ xorv;
  int cb1 = ((64 + (lane >> 4) * 16)) ^ xorv;

  // y: tile p covers fragment (mi=p>>2, ni=p&3), j=0..3 -> 8 dwordx2/tile.
  const float2* y2 = (const float2*)y;
  int r_l = (lane >> 4) * 4;
  int c_l = lane & 15;
  int yrb = bm0 + wr * 64 + r_l;
  int yb[4];
#pragma unroll
  for (int ni = 0; ni < 4; ++ni) {
    int col = bn0 + wc * 64 + ni * 16 + c_l;
    yb[ni] = ((col >> 5) << 6) + (col & 31);
  }
  float2 yin[2][8];  // 2-slot rotating window

#define STAGE_P1(buf, ks)                                                      \
  {                                                                            \
    int k0 = (ks) * BK;                                                        \
    char* ab = smem + (buf) * 49152 + ldsOff;                                  \
    gload_lds16(aSrc + k0, ab);                                                \
    gload_lds16(aSrc + (size_t)64 * KDIM + k0, ab + 8192);                     \
    gload_lds16(aSrc + (size_t)128 * KDIM + k0, ab + 16384);                   \
  }
#define STAGE_P2(buf, ks)                                                      \
  {                                                                            \
    int k0 = (ks) * BK;                                                        \
    char* ab = smem + (buf) * 49152 + ldsOff;                                  \
    char* bb = smem + (buf) * 49152 + 32768 + ldsOff;                          \
    gload_lds16(aSrc + (size_t)192 * KDIM + k0, ab + 24576);                   \
    gload_lds16(bSrc + k0, bb);                                                \
    gload_lds16(bSrc + (size_t)64 * KDIM + k0, bb + 8192);                     \
  }

#define YLD2(slot, s, q)                                                       \
  {                                                                            \
    const float2* pp = y2 +                                                    \
        (size_t)(yrb + (((q) >> 4) * 16) + ((q) & 3)) * 2048 + yb[((q) >> 2) & 3]; \
    asm volatile("global_load_dwordx2 %0, %1, off"                             \
                 : "=v"(yin[slot][2 * (s)]) : "v"(pp) : "memory");             \
    asm volatile("global_load_dwordx2 %0, %1, off offset:256"                  \
                 : "=v"(yin[slot][2 * (s) + 1]) : "v"(pp) : "memory");         \
  }
#define YLOAD8(slot, t)                                                        \
  { YLD2(slot, 0, 4 * (t)) YLD2(slot, 1, 4 * (t) + 1)                          \
    YLD2(slot, 2, 4 * (t) + 2) YLD2(slot, 3, 4 * (t) + 3) }
// tile p's 4 y-values are the 4 j's of fragment acc[p>>2][p&3]
#define YCONS4(slot, p)                                                        \
  {                                                                            \
    _Pragma("unroll")                                                          \
    for (int s = 0; s < 4; ++s)                                                \
      acc[(p) >> 2][(p) & 3][s] +=                                             \
          0.25f * ((yin[slot][2 * s].x + yin[slot][2 * s].y) +                 \
                   (yin[slot][2 * s + 1].x + yin[slot][2 * s + 1].y));         \
  }

#define FRAGS(av, bv, cbv, Ab, Bb)                                             \
  {                                                                            \
    _Pragma("unroll")                                                          \
    for (int mi = 0; mi < 4; ++mi)                                             \
      av[mi] = *(const bf16x8*)((Ab) + (wr * 64 + mi * 16) * 128 + rbase + (cbv)); \
    _Pragma("unroll")                                                          \
    for (int ni = 0; ni < 4; ++ni)                                             \
      bv[ni] = *(const bf16x8*)((Bb) + (wc * 64 + ni * 16) * 128 + rbase + (cbv)); \
  }
#define MM16(av, bv)                                                           \
  {                                                                            \
    _Pragma("unroll")                                                          \
    for (int mi = 0; mi < 4; ++mi)                                             \
      _Pragma("unroll")                                                        \
      for (int ni = 0; ni < 4; ++ni)                                           \
        acc[mi][ni] = __builtin_amdgcn_mfma_f32_16x16x32_bf16(                 \
            av[mi], bv[ni], acc[mi][ni], 0, 0, 0);                             \
  }

  // Per K-tile: wait vmcnt(8) (S_t retired, only Y_{t-1} in flight) -> barrier
  // -> consume Y_{t-2} -> {frags kk0 | stage P1(t+1)} lgkm0 MFMA -> {frags kk1
  // | stage P2(t+1) | YLOAD(t)} lgkm0 MFMA.  S_{t+1} writes the buffer tile
  // t-1 vacated (safe: issued after t's barrier). Never drains mid-loop.
#define TILE(t, WSTR)                                                          \
  {                                                                            \
    asm volatile(WSTR ::: "memory");                                           \
    __builtin_amdgcn_sched_barrier(0);                                         \
    __builtin_amdgcn_s_barrier();                                              \
    if ((t) >= 2) YCONS4(((t) - 2) & 1, (t) - 2);                              \
    const char* Ab = smem + ((t) & 1) * 49152;                                 \
    const char* Bb = Ab + 32768;                                               \
    bf16x8 a0[4], b0[4];                                                       \
    FRAGS(a0, b0, cb0, Ab, Bb);                                                \
    if ((t) < 15) STAGE_P1(((t) + 1) & 1, (t) + 1);                            \
    asm volatile("s_waitcnt lgkmcnt(0)" ::: "memory");                         \
    __builtin_amdgcn_sched_barrier(0);                                         \
    __builtin_amdgcn_s_setprio(1);                                             \
    MM16(a0, b0);                                                              \
    __builtin_amdgcn_s_setprio(0);                                             \
    bf16x8 a1[4], b1[4];                                                       \
    FRAGS(a1, b1, cb1, Ab, Bb);                                                \
    if ((t) < 15) STAGE_P2(((t) + 1) & 1, (t) + 1);                            \
    YLOAD8((t) & 1, t);                                                        \
    asm volatile("s_waitcnt lgkmcnt(0)" ::: "memory");                         \
    __builtin_amdgcn_sched_barrier(0);                                         \
    __builtin_amdgcn_s_setprio(1);                                             \
    MM16(a1, b1);                                                              \
    __builtin_amdgcn_s_setprio(0);                                             \
  }

  // prologue: stage tile 0 fully
  STAGE_P1(0, 0);
  STAGE_P2(0, 0);

  TILE(0,  "s_waitcnt vmcnt(0)")
  TILE(1,  "s_waitcnt vmcnt(8)")
  TILE(2,  "s_waitcnt vmcnt(8)")
  TILE(3,  "s_waitcnt vmcnt(8)")
  TILE(4,  "s_waitcnt vmcnt(8)")
  TILE(5,  "s_waitcnt vmcnt(8)")
  TILE(6,  "s_waitcnt vmcnt(8)")
  TILE(7,  "s_waitcnt vmcnt(8)")
  TILE(8,  "s_waitcnt vmcnt(8)")
  TILE(9,  "s_waitcnt vmcnt(8)")
  TILE(10, "s_waitcnt vmcnt(8)")
  TILE(11, "s_waitcnt vmcnt(8)")
  TILE(12, "s_waitcnt vmcnt(8)")
  TILE(13, "s_waitcnt vmcnt(8)")
  TILE(14, "s_waitcnt vmcnt(8)")
  TILE(15, "s_waitcnt vmcnt(8)")

  asm volatile("s_waitcnt vmcnt(0)" ::: "memory");
  __builtin_amdgcn_sched_barrier(0);
  YCONS4(0, 14);
  YCONS4(1, 15);

  // epilogue: acc holds gemm + pooled y; add bias, store, block sum
  float tsum = 0.f;
  float bpv[4];
#pragma unroll
  for (int ni = 0; ni < 4; ++ni) bpv[ni] = biasp[bn0 + wc * 64 + ni * 16 + c_l];
#pragma unroll
  for (int mi = 0; mi < 4; ++mi) {
#pragma unroll
    for (int ni = 0; ni < 4; ++ni) {
      int col = bn0 + wc * 64 + ni * 16 + c_l;
#pragma unroll
      for (int j = 0; j < 4; ++j) {
        int row = bm0 + wr * 64 + mi * 16 + r_l + j;
        float val = acc[mi][ni][j] + bpv[ni];
        size_t o = (size_t)row * NP + col;
        if (use16) ph[o] = (_Float16)val;
        else out[o] = val;
        tsum += val;
      }
    }
  }
#pragma unroll
  for (int off = 32; off > 0; off >>= 1) tsum += __shfl_down(tsum, off);
  float* sm = (float*)smem;
  __syncthreads();
  if (lane == 0) sm[wid] = tsum;
  __syncthreads();
  if (tid == 0)
    partials[bid] = ((sm[0] + sm[1]) + (sm[2] + sm[3])) +
                    ((sm[4] + sm[5]) + (sm[6] + sm[7]));
}

// ---- kernel 3: redundant per-block reduce of 256 partials; scale to f32 out ----
__global__ void k_norm(float* __restrict__ out, const _Float16* __restrict__ ph,
                       const float* __restrict__ partials, int use16) {
  __shared__ float s[256];
  int t = threadIdx.x;
  s[t] = partials[t];
  __syncthreads();
#pragma unroll
  for (int off = 128; off > 0; off >>= 1) {
    if (t < off) s[t] += s[t + off];
    __syncthreads();
  }
  float inv = 8388608.0f / s[0];  // (B*NP)/total
  int i = blockIdx.x * 256 + t;   // float4 index
  float4* o4 = (float4*)out;
  if (use16) {
    f16x4 hv = ((const f16x4*)ph)[i];
    float4 v;
    v.x = (float)hv[0] * inv;
    v.y = (float)hv[1] * inv;
    v.z = (float)hv[2] * inv;
    v.w = (float)hv[3] * inv;
    o4[i] = v;
  } else {
    float4 v = o4[i];
    v.x *= inv; v.y *= inv; v.z *= inv; v.w *= inv;
    o4[i] = v;
  }
}

extern "C" void kernel_launch(void* const* d_in, const int* in_sizes, int n_in,
                              void* d_out, int out_size, void* d_ws, size_t ws_size,
                              hipStream_t stream) {
  (void)in_sizes; (void)n_in; (void)out_size;
  const float* x = (const float*)d_in[0];
  const float* y = (const float*)d_in[1];
  const float* W = (const float*)d_in[2];
  const float* bias = (const float*)d_in[3];
  float* out = (float*)d_out;

  char* ws = (char*)d_ws;
  unsigned short* xb = (unsigned short*)(ws);                 // 16 MiB
  unsigned short* wp = (unsigned short*)(ws + 16777216);      // 2 MiB
  float* biasp = (float*)(ws + 16777216 + 2097152);           // 4 KiB
  float* partials = (float*)(ws + 16777216 + 2097152 + 4096); // 1 KiB
  _Float16* ph = (_Float16*)(ws + 20971520);                  // 16 MiB
  int use16 = (ws_size >= (size_t)20971520 + 16777216) ? 1 : 0;

  hipLaunchKernelGGL(k_prep, dim3(5120), dim3(256), 0, stream, x, W, bias, xb, wp, biasp);
  hipLaunchKernelGGL(k_gemm, dim3(NBLK), dim3(512), 0, stream, xb, wp, biasp, y, out, ph, partials, use16);
  hipLaunchKernelGGL(k_norm, dim3(8192), dim3(256), 0, stream, out, ph, partials, use16);
}